// Round 9
// baseline (808.434 us; speedup 1.0000x reference)
//
#include <hip/hip_runtime.h>
#include <hip/hip_bf16.h>
#include <math.h>

// ---------------- problem constants ----------------
constexpr int NN = 50000;   // nodes
constexpr int EE = 800000;  // edges

// ---------------- workspace layout (float offsets) ----------------
constexpr int OFF_WAOUT   = 0;      // [128] f32
constexpr int OFF_BE      = 128;    // [128] f32
constexpr int OFF_BFIN    = 256;    // [128] f32
constexpr int OFF_BAOUT   = 384;    // [1] (pad to 400)
// bf16 transposed weight tables ([o][k])
constexpr int OFF_WNODEBF = 400;                    // 512*128 ushort = 32768 fl
constexpr int OFF_WFINBF  = OFF_WNODEBF + 32768;    // 128*384 ushort = 24576 fl
constexpr int OFF_WMLPBF  = OFF_WFINBF + 24576;     // 2*128*128 ushort = 16384 fl
constexpr int OFF_WAMULBF = OFF_WMLPBF + 16384;     // 128*128 ushort = 8192 fl
// big arrays (bf16 combined node tables: one contiguous 512 B row per node per side)
constexpr int OFF_FSRC    = OFF_WAMULBF + 8192;     // [N][256] bf16 : feat | S_src
constexpr int OFF_FDST    = OFF_FSRC + NN*128;      // [N][256] bf16 : feat | S_dst  (dead after gemm_edge)
constexpr int OFF_HBF     = OFF_FDST + NN*128;      // [N][256] bf16 : h | h2
constexpr int OFF_SEV     = OFF_HBF + NN*128;       // [E] f32, dst-sorted e
constexpr int OFF_STARTS  = OFF_SEV + EE;           // [N+1] int (+pad)
constexpr int OFF_HIST    = OFF_STARTS + NN + 8;    // [N] int
constexpr int OFF_CURSOR  = OFF_HIST + NN;          // [N] int
constexpr int OFF_SSRCD   = OFF_CURSOR + NN;        // [E] int2 (src,dst sorted by dst)
constexpr int OFF_NEIGHBF = OFF_FDST;               // [N][256] bf16 (neigh|neigh2) -- aliases FDST (dead by then)

typedef __attribute__((ext_vector_type(8))) short bf16x8;
typedef __attribute__((ext_vector_type(4))) float f32x4;

// ---------------- device helpers ----------------
// fast GELU (tanh form via sigmoid): max |err| vs exact erf-gelu ~3e-4
__device__ __forceinline__ float gelu_f(float x) {
    float x2 = x * x;
    float u = x * (1.5957691216f + 0.07135481283f * x2);
    return x / (1.0f + __expf(-u));
}
__device__ __forceinline__ float leaky_f(float x) {
    return x > 0.0f ? x : 0.2f * x;
}
__device__ __forceinline__ unsigned short f2bf(float x) {
    unsigned u = __float_as_uint(x);
    return (unsigned short)((u + 0x7fffu + ((u >> 16) & 1u)) >> 16);
}
__device__ __forceinline__ float bf2f(unsigned short b) {
    return __uint_as_float(((unsigned)b) << 16);
}
__device__ __forceinline__ unsigned pk_bf16(float lo, float hi) {
    __hip_bfloat16 l = __float2bfloat16(lo);
    __hip_bfloat16 h = __float2bfloat16(hi);
    unsigned short lu = *reinterpret_cast<unsigned short*>(&l);
    unsigned short hu = *reinterpret_cast<unsigned short*>(&h);
    return (unsigned)lu | ((unsigned)hu << 16);
}
__device__ __forceinline__ unsigned mulpack(unsigned a, unsigned b) {
    float a0 = __uint_as_float(a << 16), a1 = __uint_as_float(a & 0xffff0000u);
    float b0 = __uint_as_float(b << 16), b1 = __uint_as_float(b & 0xffff0000u);
    return pk_bf16(a0 * b0, a1 * b1);
}
__device__ __forceinline__ unsigned addpack(unsigned a, unsigned b) {
    float a0 = __uint_as_float(a << 16), a1 = __uint_as_float(a & 0xffff0000u);
    float b0 = __uint_as_float(b << 16), b1 = __uint_as_float(b & 0xffff0000u);
    return pk_bf16(a0 + b0, a1 + b1);
}
__device__ __forceinline__ float block_sum128(float v, float* sbuf) {
    #pragma unroll
    for (int o = 32; o > 0; o >>= 1) v += __shfl_down(v, o, 64);
    int lane = threadIdx.x & 63, w = threadIdx.x >> 6;
    if (lane == 0) sbuf[w] = v;
    __syncthreads();
    float r = sbuf[0] + sbuf[1];
    __syncthreads();
    return r;
}

// ---------------- weight normalization: writes bf16 transposed tables directly ----------------
struct WnormArgs {
    const float *asrc_v, *asrc_g, *asrc_b;
    const float *adst_v, *adst_g, *adst_b;
    const float *asub_v, *asub_g, *asub_b;
    const float *amul_v, *amul_g, *amul_b;
    const float *aout_v, *aout_g, *aout_b;
    const float *pool_v, *pool_g, *pool_b;
    const float *pool2_v, *pool2_g, *pool2_b;
    const float *self_v, *self_g, *self_b;
    const float *neigh_v, *neigh_g, *neigh_b;
    const float *neigh2_v, *neigh2_g, *neigh2_b;
    const float *mlp_v, *mlp_g, *mlp_b;
    float* ws;
};

__global__ __launch_bounds__(128) void wnorm_kernel(WnormArgs a) {
    __shared__ float sbuf[2];
    int bid = blockIdx.x, i = threadIdx.x;
    float* ws = a.ws;
    unsigned short* wnodebf = (unsigned short*)(ws + OFF_WNODEBF);
    unsigned short* wfinbf  = (unsigned short*)(ws + OFF_WFINBF);
    unsigned short* wmlpbf  = (unsigned short*)(ws + OFF_WMLPBF);
    unsigned short* wamulbf = (unsigned short*)(ws + OFF_WAMULBF);
    if (bid < 1280) {
        int o = bid & 127, grp = bid >> 7;
        const float *v1 = nullptr, *g1 = nullptr, *v2 = nullptr, *g2 = nullptr;
        float sgn2 = 1.0f; unsigned short* dst = nullptr;
        switch (grp) {
            case 0: v1=a.asrc_v; g1=a.asrc_g; v2=a.asub_v; g2=a.asub_g; sgn2= 1.f; dst=&wnodebf[o*128];        break;
            case 1: v1=a.adst_v; g1=a.adst_g; v2=a.asub_v; g2=a.asub_g; sgn2=-1.f; dst=&wnodebf[(128+o)*128];  break;
            case 2: v1=a.pool_v;  g1=a.pool_g;  dst=&wnodebf[(256+o)*128];  break;
            case 3: v1=a.pool2_v; g1=a.pool2_g; dst=&wnodebf[(384+o)*128];  break;
            case 4: v1=a.amul_v;  g1=a.amul_g;  dst=&wamulbf[o*128];        break;
            case 5: v1=a.neigh_v; g1=a.neigh_g; dst=&wfinbf[o*384];         break;
            case 6: v1=a.neigh2_v;g1=a.neigh2_g;dst=&wfinbf[o*384+128];     break;
            case 7: v1=a.self_v;  g1=a.self_g;  dst=&wfinbf[o*384+256];     break;
            case 8: v1=a.mlp_v;        g1=a.mlp_g;     dst=&wmlpbf[o*128];         break;
            case 9: v1=a.mlp_v+16384;  g1=a.mlp_g+128; dst=&wmlpbf[16384+o*128];   break;
        }
        float x1 = v1[o*128 + i];
        float n1 = sqrtf(block_sum128(x1*x1, sbuf));
        float w = g1[o] * x1 / n1;
        if (v2) {
            float x2 = v2[o*128 + i];
            float n2 = sqrtf(block_sum128(x2*x2, sbuf));
            w += sgn2 * g2[o] * x2 / n2;
        }
        dst[i] = f2bf(w);
    } else {
        float v = a.aout_v[i];
        float n = sqrtf(block_sum128(v*v, sbuf));
        ws[OFF_WAOUT + i] = a.aout_g[0] * v / n;
        ws[OFF_BE + i]    = a.asrc_b[i] + a.adst_b[i] + a.asub_b[i] + a.amul_b[i];
        ws[OFF_BFIN + i]  = a.self_b[i] + a.neigh_b[i] + a.neigh2_b[i];
        if (i == 0) ws[OFF_BAOUT] = a.aout_b[0];
    }
}

// ---------------- feat -> bf16 into both combined tables; also zero hist ----------------
__global__ __launch_bounds__(256) void convert_feat_kernel(const float* __restrict__ feat,
                                                           float* __restrict__ ws) {
    unsigned short* fsrc = (unsigned short*)(ws + OFF_FSRC);
    unsigned short* fdst = (unsigned short*)(ws + OFF_FDST);
    int g = blockIdx.x * 256 + threadIdx.x;
    int i = g * 8;                       // element index into feat (NN*128)
    int row = i >> 7, col = i & 127;
    float4 v0 = ((const float4*)feat)[i >> 2];
    float4 v1 = ((const float4*)feat)[(i >> 2) + 1];
    uint4 p;
    p.x = pk_bf16(v0.x, v0.y);
    p.y = pk_bf16(v0.z, v0.w);
    p.z = pk_bf16(v1.x, v1.y);
    p.w = pk_bf16(v1.z, v1.w);
    *(uint4*)&fsrc[row * 256 + col] = p;
    *(uint4*)&fdst[row * 256 + col] = p;
    if (g < NN) ((int*)(ws + OFF_HIST))[g] = 0;
}

// ---------------- CSR-by-dst construction ----------------
__global__ __launch_bounds__(256) void hist_kernel(const int* __restrict__ dst, float* __restrict__ ws) {
    int e = blockIdx.x * 256 + threadIdx.x;
    if (e < EE) atomicAdd(&((int*)(ws + OFF_HIST))[dst[e]], 1);
}

__global__ __launch_bounds__(1024) void scan_kernel(float* __restrict__ ws) {
    __shared__ int sp[1024];
    const int* hist = (const int*)(ws + OFF_HIST);
    int* starts = (int*)(ws + OFF_STARTS);
    int* cursor = (int*)(ws + OFF_CURSOR);
    int t = threadIdx.x;
    const int C = 49;
    int base = t * C;
    int local = 0;
    for (int j = 0; j < C; ++j) { int idx = base + j; if (idx < NN) local += hist[idx]; }
    sp[t] = local;
    __syncthreads();
    for (int o = 1; o < 1024; o <<= 1) {
        int v = (t >= o) ? sp[t - o] : 0;
        __syncthreads();
        sp[t] += v;
        __syncthreads();
    }
    int run = sp[t] - local;
    for (int j = 0; j < C; ++j) {
        int idx = base + j;
        if (idx < NN) { starts[idx] = run; cursor[idx] = run; run += hist[idx]; }
    }
    if (t == 0) starts[NN] = EE;
}

__global__ __launch_bounds__(256) void scatteridx_kernel(const int* __restrict__ src,
                                                         const int* __restrict__ dst,
                                                         float* __restrict__ ws) {
    int e = blockIdx.x * 256 + threadIdx.x;
    if (e >= EE) return;
    int d = dst[e];
    int pos = atomicAdd(&((int*)(ws + OFF_CURSOR))[d], 1);
    ((int2*)(ws + OFF_SSRCD))[pos] = make_int2(src[e], d);
}

// ---------------- node GEMM (MFMA): gy 0 -> S_src (fsrc hi), 1 -> S_dst (fdst hi), 2/3 -> h/h2 ----------------
__global__ __launch_bounds__(256) void gemm_node_mfma(const float* __restrict__ pool_b,
                                                      const float* __restrict__ pool2_b,
                                                      float* __restrict__ ws) {
    __shared__ unsigned short As[64 * 136];
    unsigned short* fsrc = (unsigned short*)(ws + OFF_FSRC);
    unsigned short* fdst = (unsigned short*)(ws + OFF_FDST);
    unsigned short* hbf  = (unsigned short*)(ws + OFF_HBF);
    const unsigned short* wnodebf = (const unsigned short*)(ws + OFF_WNODEBF);
    int tid = threadIdx.x;
    int row0 = blockIdx.x * 64, gy = blockIdx.y;
    #pragma unroll
    for (int it = 0; it < 4; ++it) {
        int idx = tid + it * 256;
        int r = idx >> 4, u = idx & 15;
        int rr = min(row0 + r, NN - 1);
        *(uint4*)&As[r * 136 + u * 8] = *(const uint4*)&fsrc[rr * 256 + u * 8];
    }
    __syncthreads();
    int lane = tid & 63, w = tid >> 6;
    int quad = lane >> 4, l15 = lane & 15;
    const unsigned short* B = wnodebf + gy * 128 * 128;
    f32x4 acc[8] = {};
    #pragma unroll 1
    for (int ks = 0; ks < 4; ++ks) {
        bf16x8 a = *(const bf16x8*)&As[(w * 16 + l15) * 136 + ks * 32 + quad * 8];
        #pragma unroll
        for (int t = 0; t < 8; ++t) {
            bf16x8 b = *(const bf16x8*)&B[(t * 16 + l15) * 128 + ks * 32 + quad * 8];
            acc[t] = __builtin_amdgcn_mfma_f32_16x16x32_bf16(a, b, acc[t], 0, 0, 0);
        }
    }
    #pragma unroll
    for (int reg = 0; reg < 4; ++reg) {
        int row = row0 + w * 16 + quad * 4 + reg;
        if (row >= NN) continue;
        #pragma unroll
        for (int t = 0; t < 8; ++t) {
            int col = t * 16 + l15;
            float v = acc[t][reg];
            if (gy == 0)      fsrc[row * 256 + 128 + col] = f2bf(v);
            else if (gy == 1) fdst[row * 256 + 128 + col] = f2bf(v);
            else if (gy == 2) hbf[row * 256 + col]        = f2bf(gelu_f(v + pool_b[col]));
            else              hbf[row * 256 + 128 + col]  = f2bf(gelu_f(v + pool2_b[col]));
        }
    }
}

// ---------------- edge GEMM (bf16 MFMA, dst-sorted, combined-row gathers) -> sev ----------------
__global__ __launch_bounds__(256) void gemm_edge(const unsigned short* __restrict__ fsrc,
                                                 const unsigned short* __restrict__ fdst,
                                                 const unsigned short* __restrict__ wamulbf,
                                                 float* __restrict__ ws) {
    __shared__ unsigned short As[64 * 136];
    __shared__ unsigned short Sbf[64 * 136];
    __shared__ float waout_s[128], be_s[128];
    int tid = threadIdx.x;
    int e0 = blockIdx.x * 64;
    const int2* ssrcd = (const int2*)(ws + OFF_SSRCD);
    if (tid < 128) { waout_s[tid] = ws[OFF_WAOUT + tid]; be_s[tid] = ws[OFF_BE + tid]; }
    float b_aout = ws[OFF_BAOUT];
    float* e_out = ws + OFF_SEV;

    // stage: 2 contiguous 512 B rows per edge (src-side, dst-side)
    #pragma unroll
    for (int it = 0; it < 4; ++it) {
        int idx = tid + it * 256;
        int r = idx >> 4, u = idx & 15;
        int2 sd = ssrcd[e0 + r];
        int s = sd.x, d = sd.y;
        uint4 av = *(const uint4*)&fsrc[s * 256 + u * 8];
        uint4 bv = *(const uint4*)&fdst[d * 256 + u * 8];
        uint4 m;
        m.x = mulpack(av.x, bv.x); m.y = mulpack(av.y, bv.y);
        m.z = mulpack(av.z, bv.z); m.w = mulpack(av.w, bv.w);
        *(uint4*)&As[r * 136 + u * 8] = m;
        uint4 s1 = *(const uint4*)&fsrc[s * 256 + 128 + u * 8];
        uint4 s2 = *(const uint4*)&fdst[d * 256 + 128 + u * 8];
        uint4 sm;
        sm.x = addpack(s1.x, s2.x); sm.y = addpack(s1.y, s2.y);
        sm.z = addpack(s1.z, s2.z); sm.w = addpack(s1.w, s2.w);
        *(uint4*)&Sbf[r * 136 + u * 8] = sm;
    }
    __syncthreads();

    int lane = tid & 63, w = tid >> 6;
    int quad = lane >> 4, l15 = lane & 15;
    f32x4 acc[8] = {};
    #pragma unroll 1
    for (int ks = 0; ks < 4; ++ks) {
        bf16x8 a = *(const bf16x8*)&As[(w * 16 + l15) * 136 + ks * 32 + quad * 8];
        #pragma unroll
        for (int t = 0; t < 8; ++t) {
            bf16x8 b = *(const bf16x8*)&wamulbf[(t * 16 + l15) * 128 + ks * 32 + quad * 8];
            acc[t] = __builtin_amdgcn_mfma_f32_16x16x32_bf16(a, b, acc[t], 0, 0, 0);
        }
    }

    #pragma unroll
    for (int reg = 0; reg < 4; ++reg) {
        int r = w * 16 + quad * 4 + reg;
        float partial = 0.0f;
        #pragma unroll
        for (int t = 0; t < 8; ++t) {
            int col = t * 16 + l15;
            float v = acc[t][reg] + bf2f(Sbf[r * 136 + col]) + be_s[col];
            partial += gelu_f(v) * waout_s[col];
        }
        partial += __shfl_xor(partial, 1, 16);
        partial += __shfl_xor(partial, 2, 16);
        partial += __shfl_xor(partial, 4, 16);
        partial += __shfl_xor(partial, 8, 16);
        if (l15 == 0) e_out[e0 + r] = leaky_f(partial + b_aout);
    }
}

// ---------------- segmented reduction -> neighbf bf16 [N][256], 4-deep pipelined ----------------
__global__ __launch_bounds__(256) void segreduce_kernel(float* __restrict__ ws) {
    int n = blockIdx.x * 4 + (threadIdx.x >> 6);
    int lane = threadIdx.x & 63;
    const int* starts = (const int*)(ws + OFF_STARTS);
    const int2* ssrcd = (const int2*)(ws + OFF_SSRCD);
    const float* sev = ws + OFF_SEV;
    const unsigned short* hbf = (const unsigned short*)(ws + OFF_HBF);
    unsigned short* neighbf = (unsigned short*)(ws + OFF_NEIGHBF);
    int s0 = starts[n], s1 = starts[n + 1];
    float2 mx = make_float2(-INFINITY, -INFINITY);
    float2 sm = make_float2(0.f, 0.f);
    int i = s0;
    for (; i + 4 <= s1; i += 4) {
        int sA = ssrcd[i].x, sB = ssrcd[i+1].x, sC = ssrcd[i+2].x, sD = ssrcd[i+3].x;
        float eA = sev[i], eB = sev[i+1], eC = sev[i+2], eD = sev[i+3];
        unsigned hA  = *(const unsigned*)&hbf[sA * 256 + lane * 2];
        unsigned gA  = *(const unsigned*)&hbf[sA * 256 + 128 + lane * 2];
        unsigned hB  = *(const unsigned*)&hbf[sB * 256 + lane * 2];
        unsigned gB  = *(const unsigned*)&hbf[sB * 256 + 128 + lane * 2];
        unsigned hC  = *(const unsigned*)&hbf[sC * 256 + lane * 2];
        unsigned gC  = *(const unsigned*)&hbf[sC * 256 + 128 + lane * 2];
        unsigned hD  = *(const unsigned*)&hbf[sD * 256 + lane * 2];
        unsigned gD  = *(const unsigned*)&hbf[sD * 256 + 128 + lane * 2];
        mx.x = fmaxf(mx.x, eA * bf2f((unsigned short)(hA & 0xffffu)));
        mx.y = fmaxf(mx.y, eA * bf2f((unsigned short)(hA >> 16)));
        sm.x += eA * bf2f((unsigned short)(gA & 0xffffu));
        sm.y += eA * bf2f((unsigned short)(gA >> 16));
        mx.x = fmaxf(mx.x, eB * bf2f((unsigned short)(hB & 0xffffu)));
        mx.y = fmaxf(mx.y, eB * bf2f((unsigned short)(hB >> 16)));
        sm.x += eB * bf2f((unsigned short)(gB & 0xffffu));
        sm.y += eB * bf2f((unsigned short)(gB >> 16));
        mx.x = fmaxf(mx.x, eC * bf2f((unsigned short)(hC & 0xffffu)));
        mx.y = fmaxf(mx.y, eC * bf2f((unsigned short)(hC >> 16)));
        sm.x += eC * bf2f((unsigned short)(gC & 0xffffu));
        sm.y += eC * bf2f((unsigned short)(gC >> 16));
        mx.x = fmaxf(mx.x, eD * bf2f((unsigned short)(hD & 0xffffu)));
        mx.y = fmaxf(mx.y, eD * bf2f((unsigned short)(hD >> 16)));
        sm.x += eD * bf2f((unsigned short)(gD & 0xffffu));
        sm.y += eD * bf2f((unsigned short)(gD >> 16));
    }
    for (; i < s1; ++i) {
        int s = ssrcd[i].x;
        float ev = sev[i];
        unsigned hv  = *(const unsigned*)&hbf[s * 256 + lane * 2];
        unsigned h2v = *(const unsigned*)&hbf[s * 256 + 128 + lane * 2];
        mx.x = fmaxf(mx.x, ev * bf2f((unsigned short)(hv & 0xffffu)));
        mx.y = fmaxf(mx.y, ev * bf2f((unsigned short)(hv >> 16)));
        sm.x += ev * bf2f((unsigned short)(h2v & 0xffffu));
        sm.y += ev * bf2f((unsigned short)(h2v >> 16));
    }
    int cnt = s1 - s0;
    if (cnt == 0) { mx.x = 0.f; mx.y = 0.f; }
    float ic = 1.0f / (float)max(cnt, 1);
    *(unsigned*)&neighbf[n * 256 + lane * 2] = pk_bf16(mx.x, mx.y);
    *(unsigned*)&neighbf[n * 256 + 128 + lane * 2] = pk_bf16(sm.x * ic, sm.y * ic);
}

// ---------------- final GEMM (MFMA, K=384, single-stage LDS) -> out f32 ----------------
__global__ __launch_bounds__(256) void gemm_final_mfma(float* __restrict__ out,
                                                       const float* __restrict__ ws) {
    __shared__ unsigned short As[64 * 392];   // 64 rows x 384 cols bf16 (+8 pad)
    __shared__ float bfin_s[128];
    const unsigned short* neighbf = (const unsigned short*)(ws + OFF_NEIGHBF);
    const unsigned short* fsrc    = (const unsigned short*)(ws + OFF_FSRC);
    const unsigned short* wfinbf  = (const unsigned short*)(ws + OFF_WFINBF);
    int tid = threadIdx.x;
    int row0 = blockIdx.x * 64;
    if (tid < 128) bfin_s[tid] = ws[OFF_BFIN + tid];
    #pragma unroll
    for (int rg = 0; rg < 3; ++rg) {
        #pragma unroll
        for (int it = 0; it < 4; ++it) {
            int idx = tid + it * 256;
            int r = idx >> 4, u = idx & 15;
            int rr = min(row0 + r, NN - 1);
            const unsigned short* sp = (rg == 0) ? &neighbf[rr * 256 + u * 8]
                                     : (rg == 1) ? &neighbf[rr * 256 + 128 + u * 8]
                                                 : &fsrc[rr * 256 + u * 8];
            *(uint4*)&As[r * 392 + rg * 128 + u * 8] = *(const uint4*)sp;
        }
    }
    __syncthreads();
    int lane = tid & 63, w = tid >> 6;
    int quad = lane >> 4, l15 = lane & 15;
    f32x4 acc[8] = {};
    #pragma unroll 1
    for (int ks = 0; ks < 12; ++ks) {
        bf16x8 a = *(const bf16x8*)&As[(w * 16 + l15) * 392 + ks * 32 + quad * 8];
        #pragma unroll
        for (int t = 0; t < 8; ++t) {
            bf16x8 b = *(const bf16x8*)&wfinbf[(t * 16 + l15) * 384 + ks * 32 + quad * 8];
            acc[t] = __builtin_amdgcn_mfma_f32_16x16x32_bf16(a, b, acc[t], 0, 0, 0);
        }
    }
    #pragma unroll
    for (int reg = 0; reg < 4; ++reg) {
        int row = row0 + w * 16 + quad * 4 + reg;
        if (row >= NN) continue;
        #pragma unroll
        for (int t = 0; t < 8; ++t) {
            int col = t * 16 + l15;
            out[row * 128 + col] = acc[t][reg] + bfin_s[col];
        }
    }
}

// ---------------- MLP layer (MFMA, in-place on out; block reads only its own rows) ----------------
__global__ __launch_bounds__(256) void gemm_mlp_mfma(float* __restrict__ out,
                                                     const unsigned short* __restrict__ wmlp,
                                                     const float* __restrict__ bias) {
    __shared__ unsigned short As[64 * 136];
    int tid = threadIdx.x;
    int row0 = blockIdx.x * 64;
    #pragma unroll
    for (int it = 0; it < 8; ++it) {
        int idx = tid + it * 256;
        int r = idx >> 5, u = idx & 31;
        int rr = min(row0 + r, NN - 1);
        float4 v = ((const float4*)out)[rr * 32 + u];
        unsigned p0 = pk_bf16(gelu_f(v.x), gelu_f(v.y));
        unsigned p1 = pk_bf16(gelu_f(v.z), gelu_f(v.w));
        *(unsigned*)&As[r * 136 + u * 4]     = p0;
        *(unsigned*)&As[r * 136 + u * 4 + 2] = p1;
    }
    __syncthreads();
    int lane = tid & 63, w = tid >> 6;
    int quad = lane >> 4, l15 = lane & 15;
    f32x4 acc[8] = {};
    #pragma unroll 1
    for (int ks = 0; ks < 4; ++ks) {
        bf16x8 a = *(const bf16x8*)&As[(w * 16 + l15) * 136 + ks * 32 + quad * 8];
        #pragma unroll
        for (int t = 0; t < 8; ++t) {
            bf16x8 b = *(const bf16x8*)&wmlp[(t * 16 + l15) * 128 + ks * 32 + quad * 8];
            acc[t] = __builtin_amdgcn_mfma_f32_16x16x32_bf16(a, b, acc[t], 0, 0, 0);
        }
    }
    #pragma unroll
    for (int reg = 0; reg < 4; ++reg) {
        int row = row0 + w * 16 + quad * 4 + reg;
        if (row >= NN) continue;
        #pragma unroll
        for (int t = 0; t < 8; ++t) {
            int col = t * 16 + l15;
            out[row * 128 + col] += acc[t][reg] + bias[col];
        }
    }
}

// ---------------- host launch ----------------
extern "C" void kernel_launch(void* const* d_in, const int* in_sizes, int n_in,
                              void* d_out, int out_size, void* d_ws, size_t ws_size,
                              hipStream_t stream) {
    const float* feat = (const float*)d_in[0];
    WnormArgs wa;
    wa.asrc_v = (const float*)d_in[1];  wa.asrc_g = (const float*)d_in[2];  wa.asrc_b = (const float*)d_in[3];
    wa.adst_v = (const float*)d_in[4];  wa.adst_g = (const float*)d_in[5];  wa.adst_b = (const float*)d_in[6];
    wa.asub_v = (const float*)d_in[7];  wa.asub_g = (const float*)d_in[8];  wa.asub_b = (const float*)d_in[9];
    wa.amul_v = (const float*)d_in[10]; wa.amul_g = (const float*)d_in[11]; wa.amul_b = (const float*)d_in[12];
    wa.aout_v = (const float*)d_in[13]; wa.aout_g = (const float*)d_in[14]; wa.aout_b = (const float*)d_in[15];
    wa.pool_v = (const float*)d_in[16]; wa.pool_g = (const float*)d_in[17]; wa.pool_b = (const float*)d_in[18];
    wa.pool2_v= (const float*)d_in[19]; wa.pool2_g= (const float*)d_in[20]; wa.pool2_b= (const float*)d_in[21];
    wa.self_v = (const float*)d_in[22]; wa.self_g = (const float*)d_in[23]; wa.self_b = (const float*)d_in[24];
    wa.neigh_v= (const float*)d_in[25]; wa.neigh_g= (const float*)d_in[26]; wa.neigh_b= (const float*)d_in[27];
    wa.neigh2_v=(const float*)d_in[28]; wa.neigh2_g=(const float*)d_in[29]; wa.neigh2_b=(const float*)d_in[30];
    wa.mlp_v  = (const float*)d_in[31]; wa.mlp_g  = (const float*)d_in[32]; wa.mlp_b  = (const float*)d_in[33];
    const int* src = (const int*)d_in[34];
    const int* dst = (const int*)d_in[35];
    float* out = (float*)d_out;
    float* ws = (float*)d_ws;
    wa.ws = ws;
    unsigned short* fsrc    = (unsigned short*)(ws + OFF_FSRC);
    unsigned short* fdst    = (unsigned short*)(ws + OFF_FDST);
    unsigned short* wmlpbf  = (unsigned short*)(ws + OFF_WMLPBF);
    unsigned short* wamulbf = (unsigned short*)(ws + OFF_WAMULBF);

    // 1) weight-norm -> bf16 tables + bias vectors
    wnorm_kernel<<<dim3(1281), dim3(128), 0, stream>>>(wa);
    // 2) feat -> bf16 into both combined tables (+ hist zero)
    convert_feat_kernel<<<dim3(NN * 128 / (256 * 8)), dim3(256), 0, stream>>>(feat, ws);
    // 3) CSR-by-dst
    hist_kernel<<<dim3((EE + 255) / 256), dim3(256), 0, stream>>>(dst, ws);
    scan_kernel<<<dim3(1), dim3(1024), 0, stream>>>(ws);
    scatteridx_kernel<<<dim3((EE + 255) / 256), dim3(256), 0, stream>>>(src, dst, ws);
    // 4) node GEMM (MFMA): S halves of fsrc/fdst + h/h2
    gemm_node_mfma<<<dim3(782, 4), dim3(256), 0, stream>>>(wa.pool_b, wa.pool2_b, ws);
    // 5) edge GEMM (MFMA, dst-sorted, combined-row gathers) -> sev
    gemm_edge<<<dim3(EE / 64), dim3(256), 0, stream>>>(fsrc, fdst, wamulbf, ws);
    // 6) segmented reduce -> neighbf (aliases fdst; fdst dead after step 5)
    segreduce_kernel<<<dim3(NN / 4), dim3(256), 0, stream>>>(ws);
    // 7) final GEMM (MFMA) -> out f32
    gemm_final_mfma<<<dim3(782), dim3(256), 0, stream>>>(out, ws);
    // 8) two residual MLP layers (MFMA, in-place)
    gemm_mlp_mfma<<<dim3(782), dim3(256), 0, stream>>>(out, wmlpbf, wa.mlp_b);
    gemm_mlp_mfma<<<dim3(782), dim3(256), 0, stream>>>(out, wmlpbf + 16384, wa.mlp_b + 128);
}